// Round 3
// baseline (1417.715 us; speedup 1.0000x reference)
//
#include <hip/hip_runtime.h>

#define TPB 256

static inline int cdiv(int a, int b) { return (a + b - 1) / b; }

// ---------------- CSR build ----------------

__global__ void k_zero_int(int* p, int n) {
    int i = blockIdx.x * blockDim.x + threadIdx.x;
    if (i < n) p[i] = 0;
}

__global__ void k_hist(const int* __restrict__ dst, int* __restrict__ cnt, int e) {
    int i = blockIdx.x * blockDim.x + threadIdx.x;
    if (i < e) atomicAdd(&cnt[dst[i]], 1);
}

__global__ void k_dinv_from_cnt(const int* __restrict__ cnt, float* __restrict__ dinv, int n) {
    int i = blockIdx.x * blockDim.x + threadIdx.x;
    if (i < n) dinv[i] = rsqrtf((float)cnt[i] + 1.0f);  // +1 self-loop
}

__global__ void k_scan1(const int* __restrict__ cnt, int* __restrict__ offs,
                        int* __restrict__ bsum, int n) {
    __shared__ int s[256];
    int i = blockIdx.x * 256 + threadIdx.x;
    int v = (i < n) ? cnt[i] : 0;
    s[threadIdx.x] = v;
    __syncthreads();
    for (int d = 1; d < 256; d <<= 1) {
        int t = (threadIdx.x >= d) ? s[threadIdx.x - d] : 0;
        __syncthreads();
        s[threadIdx.x] += t;
        __syncthreads();
    }
    if (i < n) offs[i] = s[threadIdx.x] - v;
    if (threadIdx.x == 255) bsum[blockIdx.x] = s[255];
}

__global__ void k_scan2(int* __restrict__ bsum, int nb) {
    __shared__ int s[256];
    int v = (threadIdx.x < nb) ? bsum[threadIdx.x] : 0;
    s[threadIdx.x] = v;
    __syncthreads();
    for (int d = 1; d < 256; d <<= 1) {
        int t = (threadIdx.x >= d) ? s[threadIdx.x - d] : 0;
        __syncthreads();
        s[threadIdx.x] += t;
        __syncthreads();
    }
    if (threadIdx.x < nb) bsum[threadIdx.x] = s[threadIdx.x] - v;
}

__global__ void k_scan3(int* __restrict__ offs, const int* __restrict__ bsum,
                        int* __restrict__ cursor, int n, int e) {
    int i = blockIdx.x * blockDim.x + threadIdx.x;
    if (i < n) {
        int v = offs[i] + bsum[i >> 8];
        offs[i] = v;
        cursor[i] = v;
    }
    if (i == 0) offs[n] = e;
}

__global__ void k_fill(const int* __restrict__ src, const int* __restrict__ dst,
                       int* __restrict__ cursor, int* __restrict__ ssrc, int e) {
    int i = blockIdx.x * blockDim.x + threadIdx.x;
    if (i < e) {
        int pos = atomicAdd(&cursor[dst[i]], 1);
        ssrc[pos] = src[i];
    }
}

// ---------------- feature kernels ----------------

// G = x * dinv[row], float4-wide
template<int C>  // C = D/4 chunks per row
__global__ void k_scale(const float* __restrict__ x, const float* __restrict__ dinv,
                        float* __restrict__ G, int n) {
    int idx = blockIdx.x * blockDim.x + threadIdx.x;
    if (idx >= n * C) return;
    float d = dinv[idx / C];
    float4 v = ((const float4*)x)[idx];
    ((float4*)G)[idx] = make_float4(v.x * d, v.y * d, v.z * d, v.w * d);
}

// A[i] = (G[i] + sum_{j in N(i)} G[src_j]) * dinv[i]   — CSR gather, no atomics
template<int D>
__global__ void k_gather(const int* __restrict__ offs, const int* __restrict__ ssrc,
                         const float* __restrict__ G, const float* __restrict__ dinv,
                         float* __restrict__ A, int n) {
    constexpr int C = D / 4;
    int idx = blockIdx.x * blockDim.x + threadIdx.x;
    if (idx >= n * C) return;
    int i = idx / C;
    int c = idx & (C - 1);
    const float4* Grow = (const float4*)G;
    float4 acc = Grow[(size_t)i * C + c];   // self-loop term
    int s0 = offs[i], s1 = offs[i + 1];
    int j = s0;
    for (; j + 1 < s1; j += 2) {            // 2-way unroll: overlap two gather chains
        int sa = ssrc[j], sb = ssrc[j + 1];
        float4 ga = Grow[(size_t)sa * C + c];
        float4 gb = Grow[(size_t)sb * C + c];
        acc.x += ga.x + gb.x; acc.y += ga.y + gb.y;
        acc.z += ga.z + gb.z; acc.w += ga.w + gb.w;
    }
    if (j < s1) {
        int sa = ssrc[j];
        float4 ga = Grow[(size_t)sa * C + c];
        acc.x += ga.x; acc.y += ga.y; acc.z += ga.z; acc.w += ga.w;
    }
    float di = dinv[i];
    ((float4*)A)[(size_t)i * C + c] =
        make_float4(acc.x * di, acc.y * di, acc.z * di, acc.w * di);
}

// out = relu(A @ W + b) [* dinv[row] if SCALE] — tiled register-blocked GEMM
template<int DI, int DO, int R, bool SCALE>
__global__ void k_gemm(const float* __restrict__ A, const float* __restrict__ W,
                       const float* __restrict__ b, const float* __restrict__ dinv,
                       float* __restrict__ out, int n) {
    constexpr int CT = DO / 4;       // threads across columns (each owns 4 cols)
    constexpr int RT = TPB / CT;     // row groups
    constexpr int TM = RT * R;       // rows per block
    constexpr int K4 = DI / 4;
    constexpr int PX = K4 + 1;       // padded pitch (break bank aliasing)
    __shared__ float4 sW4[DI * CT];
    __shared__ float4 sX4[TM * PX];
    const int tid = threadIdx.x;

    const float4* Wg = (const float4*)W;
    for (int t = tid; t < DI * CT; t += TPB) sW4[t] = Wg[t];

    const int r0 = blockIdx.x * TM;
    const float4* Ag = (const float4*)A;
    for (int t = tid; t < TM * K4; t += TPB) {
        int r = t / K4, k4 = t - r * K4;
        int row = r0 + r;
        sX4[r * PX + k4] = (row < n) ? Ag[(size_t)row * K4 + k4]
                                     : make_float4(0.f, 0.f, 0.f, 0.f);
    }
    __syncthreads();

    const int c = tid & (CT - 1);
    const int rg = tid / CT;
    const int rbase = rg * R;
    float4 acc[R];
#pragma unroll
    for (int r = 0; r < R; ++r) acc[r] = make_float4(0.f, 0.f, 0.f, 0.f);

#pragma unroll
    for (int k4 = 0; k4 < K4; ++k4) {
        float4 xv[R];
#pragma unroll
        for (int r = 0; r < R; ++r) xv[r] = sX4[(rbase + r) * PX + k4];
#pragma unroll
        for (int kk = 0; kk < 4; ++kk) {
            float4 wv = sW4[(k4 * 4 + kk) * CT + c];
#pragma unroll
            for (int r = 0; r < R; ++r) {
                float xs = (kk == 0) ? xv[r].x : (kk == 1) ? xv[r].y
                         : (kk == 2) ? xv[r].z : xv[r].w;
                acc[r].x += xs * wv.x; acc[r].y += xs * wv.y;
                acc[r].z += xs * wv.z; acc[r].w += xs * wv.w;
            }
        }
    }

    float4 bc = ((const float4*)b)[c];
#pragma unroll
    for (int r = 0; r < R; ++r) {
        int row = r0 + rbase + r;
        if (row < n) {
            float4 o;
            o.x = fmaxf(acc[r].x + bc.x, 0.f);
            o.y = fmaxf(acc[r].y + bc.y, 0.f);
            o.z = fmaxf(acc[r].z + bc.z, 0.f);
            o.w = fmaxf(acc[r].w + bc.w, 0.f);
            if (SCALE) {
                float d = dinv[row];
                o.x *= d; o.y *= d; o.z *= d; o.w *= d;
            }
            ((float4*)out)[(size_t)row * CT + c] = o;
        }
    }
}

extern "C" void kernel_launch(void* const* d_in, const int* in_sizes, int n_in,
                              void* d_out, int out_size, void* d_ws, size_t ws_size,
                              hipStream_t stream) {
    const float* x   = (const float*)d_in[0];
    const int*   ei  = (const int*)d_in[1];
    const float* W1  = (const float*)d_in[2];
    const float* bb1 = (const float*)d_in[3];
    const float* W2  = (const float*)d_in[4];
    const float* bb2 = (const float*)d_in[5];
    const float* W3  = (const float*)d_in[6];
    const float* bb3 = (const float*)d_in[7];
    const float* Wl1 = (const float*)d_in[8];
    const float* bl1 = (const float*)d_in[9];
    const float* Wl2 = (const float*)d_in[10];
    const float* bl2 = (const float*)d_in[11];
    const float* Wl3 = (const float*)d_in[12];
    const float* bl3 = (const float*)d_in[13];
    float* out = (float*)d_out;

    const int n = in_sizes[0] / 16;   // 50000
    const int e = in_sizes[1] / 2;    // 800000
    const int* src = ei;
    const int* dst = ei + e;

    char* p = (char*)d_ws;
    auto alloc = [&](size_t bytes) {
        char* r = p;
        p += (bytes + 255) & ~(size_t)255;
        return r;
    };
    const int nb = cdiv(n, 256);
    float* dinv   = (float*)alloc((size_t)n * 4);
    int*   cnt    = (int*)  alloc((size_t)n * 4);
    int*   offs   = (int*)  alloc((size_t)(n + 1) * 4);
    int*   cursor = (int*)  alloc((size_t)n * 4);
    int*   bsum   = (int*)  alloc(256 * 4);
    int*   ssrc   = (int*)  alloc((size_t)e * 4);
    float* bufA   = (float*)alloc((size_t)n * 128 * 4);
    float* bufB   = (float*)alloc((size_t)n * 128 * 4);

    // ---- CSR + dinv ----
    k_zero_int<<<cdiv(n, TPB), TPB, 0, stream>>>(cnt, n);
    k_hist<<<cdiv(e, TPB), TPB, 0, stream>>>(dst, cnt, e);
    k_dinv_from_cnt<<<cdiv(n, TPB), TPB, 0, stream>>>(cnt, dinv, n);
    k_scan1<<<nb, 256, 0, stream>>>(cnt, offs, bsum, n);
    k_scan2<<<1, 256, 0, stream>>>(bsum, nb);
    k_scan3<<<cdiv(n, TPB), TPB, 0, stream>>>(offs, bsum, cursor, n, e);
    k_fill<<<cdiv(e, TPB), TPB, 0, stream>>>(src, dst, cursor, ssrc, e);

    // ---- conv1: agg(x) then 16->32 ----
    k_scale<4><<<cdiv(n * 4, TPB), TPB, 0, stream>>>(x, dinv, bufA, n);
    k_gather<16><<<cdiv(n * 4, TPB), TPB, 0, stream>>>(offs, ssrc, bufA, dinv, bufB, n);
    k_gemm<16, 32, 4, true><<<cdiv(n, 128), TPB, 0, stream>>>(bufB, W1, bb1, dinv, bufA, n);

    // ---- conv2: agg then 32->64 ----
    k_gather<32><<<cdiv(n * 8, TPB), TPB, 0, stream>>>(offs, ssrc, bufA, dinv, bufB, n);
    k_gemm<32, 64, 4, true><<<cdiv(n, 64), TPB, 0, stream>>>(bufB, W2, bb2, dinv, bufA, n);

    // ---- conv3: agg then 64->128 ----
    k_gather<64><<<cdiv(n * 16, TPB), TPB, 0, stream>>>(offs, ssrc, bufA, dinv, bufB, n);
    k_gemm<64, 128, 4, false><<<cdiv(n, 32), TPB, 0, stream>>>(bufB, W3, bb3, nullptr, bufA, n);

    // ---- dense head ----
    k_gemm<128, 64, 2, false><<<cdiv(n, 32), TPB, 0, stream>>>(bufA, Wl1, bl1, nullptr, bufB, n);
    k_gemm<64, 32, 2, false><<<cdiv(n, 64), TPB, 0, stream>>>(bufB, Wl2, bl2, nullptr, bufA, n);
    k_gemm<32, 16, 2, false><<<cdiv(n, 128), TPB, 0, stream>>>(bufA, Wl3, bl3, nullptr, out, n);
}

// Round 4
// 316.386 us; speedup vs baseline: 4.4810x; 4.4810x over previous
//
#include <hip/hip_runtime.h>

#define TPB 256

static inline int cdiv(int a, int b) { return (a + b - 1) / b; }

// ---------------- CSR build ----------------

__global__ void k_zero_int(int* p, int n) {
    int i = blockIdx.x * blockDim.x + threadIdx.x;
    if (i < n) p[i] = 0;
}

__global__ void k_hist(const int* __restrict__ dst, int* __restrict__ cnt, int e) {
    int i = blockIdx.x * blockDim.x + threadIdx.x;
    if (i < e) atomicAdd(&cnt[dst[i]], 1);
}

__global__ void k_dinv_from_cnt(const int* __restrict__ cnt, float* __restrict__ dinv, int n) {
    int i = blockIdx.x * blockDim.x + threadIdx.x;
    if (i < n) dinv[i] = rsqrtf((float)cnt[i] + 1.0f);  // +1 self-loop
}

__global__ void k_scan1(const int* __restrict__ cnt, int* __restrict__ offs,
                        int* __restrict__ bsum, int n) {
    __shared__ int s[256];
    int i = blockIdx.x * 256 + threadIdx.x;
    int v = (i < n) ? cnt[i] : 0;
    s[threadIdx.x] = v;
    __syncthreads();
    for (int d = 1; d < 256; d <<= 1) {
        int t = (threadIdx.x >= d) ? s[threadIdx.x - d] : 0;
        __syncthreads();
        s[threadIdx.x] += t;
        __syncthreads();
    }
    if (i < n) offs[i] = s[threadIdx.x] - v;
    if (threadIdx.x == 255) bsum[blockIdx.x] = s[255];
}

__global__ void k_scan2(int* __restrict__ bsum, int nb) {
    __shared__ int s[256];
    int v = (threadIdx.x < nb) ? bsum[threadIdx.x] : 0;
    s[threadIdx.x] = v;
    __syncthreads();
    for (int d = 1; d < 256; d <<= 1) {
        int t = (threadIdx.x >= d) ? s[threadIdx.x - d] : 0;
        __syncthreads();
        s[threadIdx.x] += t;
        __syncthreads();
    }
    if (threadIdx.x < nb) bsum[threadIdx.x] = s[threadIdx.x] - v;
}

__global__ void k_scan3(int* __restrict__ offs, const int* __restrict__ bsum,
                        int* __restrict__ cursor, int n, int e) {
    int i = blockIdx.x * blockDim.x + threadIdx.x;
    if (i < n) {
        int v = offs[i] + bsum[i >> 8];
        offs[i] = v;
        cursor[i] = v;
    }
    if (i == 0) offs[n] = e;
}

__global__ void k_fill(const int* __restrict__ src, const int* __restrict__ dst,
                       int* __restrict__ cursor, int* __restrict__ ssrc, int e) {
    int i = blockIdx.x * blockDim.x + threadIdx.x;
    if (i < e) {
        int pos = atomicAdd(&cursor[dst[i]], 1);
        ssrc[pos] = src[i];
    }
}

// ---------------- feature kernels ----------------

// G = x * dinv[row], float4-wide
template<int C>
__global__ void k_scale(const float* __restrict__ x, const float* __restrict__ dinv,
                        float* __restrict__ G, int n) {
    int idx = blockIdx.x * blockDim.x + threadIdx.x;
    if (idx >= n * C) return;
    float d = dinv[idx / C];
    float4 v = ((const float4*)x)[idx];
    ((float4*)G)[idx] = make_float4(v.x * d, v.y * d, v.z * d, v.w * d);
}

// A[i] = (G[i] + sum_{j in N(i)} G[src_j]) * dinv[i]   — CSR gather, no atomics
template<int D>
__global__ void __launch_bounds__(TPB)
k_gather(const int* __restrict__ offs, const int* __restrict__ ssrc,
         const float* __restrict__ G, const float* __restrict__ dinv,
         float* __restrict__ A, int n) {
    constexpr int C = D / 4;
    int idx = blockIdx.x * blockDim.x + threadIdx.x;
    if (idx >= n * C) return;
    int i = idx / C;
    int c = idx & (C - 1);
    const float4* Grow = (const float4*)G;
    float4 acc = Grow[(size_t)i * C + c];   // self-loop term
    int s0 = offs[i], s1 = offs[i + 1];
    int j = s0;
    for (; j + 1 < s1; j += 2) {
        int sa = ssrc[j], sb = ssrc[j + 1];
        float4 ga = Grow[(size_t)sa * C + c];
        float4 gb = Grow[(size_t)sb * C + c];
        acc.x += ga.x + gb.x; acc.y += ga.y + gb.y;
        acc.z += ga.z + gb.z; acc.w += ga.w + gb.w;
    }
    if (j < s1) {
        int sa = ssrc[j];
        float4 ga = Grow[(size_t)sa * C + c];
        acc.x += ga.x; acc.y += ga.y; acc.z += ga.z; acc.w += ga.w;
    }
    float di = dinv[i];
    ((float4*)A)[(size_t)i * C + c] =
        make_float4(acc.x * di, acc.y * di, acc.z * di, acc.w * di);
}

// out = relu(A @ W + b) [* dinv[row] if SCALE] — tiled register-blocked GEMM
// __launch_bounds__(TPB,2): without it the compiler capped VGPRs at 64 and the
// unrolled K-loop spilled ~2.4 KB/thread to scratch (853 MB FETCH + 947 MB
// WRITE on the 128x64 layer, round 3). unroll 2 bounds live ranges.
template<int DI, int DO, int R, bool SCALE>
__global__ void __launch_bounds__(TPB, 2)
k_gemm(const float* __restrict__ A, const float* __restrict__ W,
       const float* __restrict__ b, const float* __restrict__ dinv,
       float* __restrict__ out, int n) {
    constexpr int CT = DO / 4;       // threads across columns (each owns 4 cols)
    constexpr int RT = TPB / CT;     // row groups
    constexpr int TM = RT * R;       // rows per block
    constexpr int K4 = DI / 4;
    constexpr int PX = K4 + 1;       // padded pitch (break bank aliasing)
    __shared__ float4 sW4[DI * CT];
    __shared__ float4 sX4[TM * PX];
    const int tid = threadIdx.x;

    const float4* Wg = (const float4*)W;
    for (int t = tid; t < DI * CT; t += TPB) sW4[t] = Wg[t];

    const int r0 = blockIdx.x * TM;
    const float4* Ag = (const float4*)A;
    for (int t = tid; t < TM * K4; t += TPB) {
        int r = t / K4, k4 = t - r * K4;
        int row = r0 + r;
        sX4[r * PX + k4] = (row < n) ? Ag[(size_t)row * K4 + k4]
                                     : make_float4(0.f, 0.f, 0.f, 0.f);
    }
    __syncthreads();

    const int c = tid & (CT - 1);
    const int rg = tid / CT;
    const int rbase = rg * R;
    float4 acc[R];
#pragma unroll
    for (int r = 0; r < R; ++r) acc[r] = make_float4(0.f, 0.f, 0.f, 0.f);

#pragma unroll 2
    for (int k4 = 0; k4 < K4; ++k4) {
        float4 xv[R];
#pragma unroll
        for (int r = 0; r < R; ++r) xv[r] = sX4[(rbase + r) * PX + k4];
#pragma unroll
        for (int kk = 0; kk < 4; ++kk) {
            float4 wv = sW4[(k4 * 4 + kk) * CT + c];
#pragma unroll
            for (int r = 0; r < R; ++r) {
                float xs = (kk == 0) ? xv[r].x : (kk == 1) ? xv[r].y
                         : (kk == 2) ? xv[r].z : xv[r].w;
                acc[r].x += xs * wv.x; acc[r].y += xs * wv.y;
                acc[r].z += xs * wv.z; acc[r].w += xs * wv.w;
            }
        }
    }

    float4 bc = ((const float4*)b)[c];
#pragma unroll
    for (int r = 0; r < R; ++r) {
        int row = r0 + rbase + r;
        if (row < n) {
            float4 o;
            o.x = fmaxf(acc[r].x + bc.x, 0.f);
            o.y = fmaxf(acc[r].y + bc.y, 0.f);
            o.z = fmaxf(acc[r].z + bc.z, 0.f);
            o.w = fmaxf(acc[r].w + bc.w, 0.f);
            if (SCALE) {
                float d = dinv[row];
                o.x *= d; o.y *= d; o.z *= d; o.w *= d;
            }
            ((float4*)out)[(size_t)row * CT + c] = o;
        }
    }
}

extern "C" void kernel_launch(void* const* d_in, const int* in_sizes, int n_in,
                              void* d_out, int out_size, void* d_ws, size_t ws_size,
                              hipStream_t stream) {
    const float* x   = (const float*)d_in[0];
    const int*   ei  = (const int*)d_in[1];
    const float* W1  = (const float*)d_in[2];
    const float* bb1 = (const float*)d_in[3];
    const float* W2  = (const float*)d_in[4];
    const float* bb2 = (const float*)d_in[5];
    const float* W3  = (const float*)d_in[6];
    const float* bb3 = (const float*)d_in[7];
    const float* Wl1 = (const float*)d_in[8];
    const float* bl1 = (const float*)d_in[9];
    const float* Wl2 = (const float*)d_in[10];
    const float* bl2 = (const float*)d_in[11];
    const float* Wl3 = (const float*)d_in[12];
    const float* bl3 = (const float*)d_in[13];
    float* out = (float*)d_out;

    const int n = in_sizes[0] / 16;   // 50000
    const int e = in_sizes[1] / 2;    // 800000
    const int* src = ei;
    const int* dst = ei + e;

    char* p = (char*)d_ws;
    auto alloc = [&](size_t bytes) {
        char* r = p;
        p += (bytes + 255) & ~(size_t)255;
        return r;
    };
    const int nb = cdiv(n, 256);
    float* dinv   = (float*)alloc((size_t)n * 4);
    int*   cnt    = (int*)  alloc((size_t)n * 4);
    int*   offs   = (int*)  alloc((size_t)(n + 1) * 4);
    int*   cursor = (int*)  alloc((size_t)n * 4);
    int*   bsum   = (int*)  alloc(256 * 4);
    int*   ssrc   = (int*)  alloc((size_t)e * 4);
    float* bufA   = (float*)alloc((size_t)n * 128 * 4);
    float* bufB   = (float*)alloc((size_t)n * 128 * 4);

    // ---- CSR + dinv ----
    k_zero_int<<<cdiv(n, TPB), TPB, 0, stream>>>(cnt, n);
    k_hist<<<cdiv(e, TPB), TPB, 0, stream>>>(dst, cnt, e);
    k_dinv_from_cnt<<<cdiv(n, TPB), TPB, 0, stream>>>(cnt, dinv, n);
    k_scan1<<<nb, 256, 0, stream>>>(cnt, offs, bsum, n);
    k_scan2<<<1, 256, 0, stream>>>(bsum, nb);
    k_scan3<<<cdiv(n, TPB), TPB, 0, stream>>>(offs, bsum, cursor, n, e);
    k_fill<<<cdiv(e, TPB), TPB, 0, stream>>>(src, dst, cursor, ssrc, e);

    // ---- conv1: agg(x) then 16->32 ----
    k_scale<4><<<cdiv(n * 4, TPB), TPB, 0, stream>>>(x, dinv, bufA, n);
    k_gather<16><<<cdiv(n * 4, TPB), TPB, 0, stream>>>(offs, ssrc, bufA, dinv, bufB, n);
    k_gemm<16, 32, 4, true><<<cdiv(n, 128), TPB, 0, stream>>>(bufB, W1, bb1, dinv, bufA, n);

    // ---- conv2: agg then 32->64 ----
    k_gather<32><<<cdiv(n * 8, TPB), TPB, 0, stream>>>(offs, ssrc, bufA, dinv, bufB, n);
    k_gemm<32, 64, 4, true><<<cdiv(n, 64), TPB, 0, stream>>>(bufB, W2, bb2, dinv, bufA, n);

    // ---- conv3: agg then 64->128 ----
    k_gather<64><<<cdiv(n * 16, TPB), TPB, 0, stream>>>(offs, ssrc, bufA, dinv, bufB, n);
    k_gemm<64, 128, 4, false><<<cdiv(n, 32), TPB, 0, stream>>>(bufB, W3, bb3, nullptr, bufA, n);

    // ---- dense head ----
    k_gemm<128, 64, 2, false><<<cdiv(n, 32), TPB, 0, stream>>>(bufA, Wl1, bl1, nullptr, bufB, n);
    k_gemm<64, 32, 2, false><<<cdiv(n, 64), TPB, 0, stream>>>(bufB, Wl2, bl2, nullptr, bufA, n);
    k_gemm<32, 16, 2, false><<<cdiv(n, 128), TPB, 0, stream>>>(bufA, Wl3, bl3, nullptr, out, n);
}

// Round 5
// 304.773 us; speedup vs baseline: 4.6517x; 1.0381x over previous
//
#include <hip/hip_runtime.h>

#define TPB 256

typedef _Float16 half_t;
typedef _Float16 half4 __attribute__((ext_vector_type(4)));

static inline int cdiv(int a, int b) { return (a + b - 1) / b; }

// ---------------- CSR build ----------------

__global__ void k_zero_int(int* p, int n) {
    int i = blockIdx.x * blockDim.x + threadIdx.x;
    if (i < n) p[i] = 0;
}

__global__ void k_hist(const int* __restrict__ dst, int* __restrict__ cnt, int e) {
    int i = blockIdx.x * blockDim.x + threadIdx.x;
    if (i < e) atomicAdd(&cnt[dst[i]], 1);
}

// per-256-block exclusive scan + block sums; also emits dinv = rsqrt(deg+1)
__global__ void k_scan1(const int* __restrict__ cnt, int* __restrict__ offs,
                        int* __restrict__ bsum, float* __restrict__ dinv, int n) {
    __shared__ int s[256];
    int i = blockIdx.x * 256 + threadIdx.x;
    int v = (i < n) ? cnt[i] : 0;
    if (i < n) dinv[i] = rsqrtf((float)v + 1.0f);   // +1 self-loop
    s[threadIdx.x] = v;
    __syncthreads();
    for (int d = 1; d < 256; d <<= 1) {
        int t = (threadIdx.x >= d) ? s[threadIdx.x - d] : 0;
        __syncthreads();
        s[threadIdx.x] += t;
        __syncthreads();
    }
    if (i < n) offs[i] = s[threadIdx.x] - v;
    if (threadIdx.x == 255) bsum[blockIdx.x] = s[255];
}

__global__ void k_scan2(int* __restrict__ bsum, int nb) {
    __shared__ int s[256];
    int v = (threadIdx.x < nb) ? bsum[threadIdx.x] : 0;
    s[threadIdx.x] = v;
    __syncthreads();
    for (int d = 1; d < 256; d <<= 1) {
        int t = (threadIdx.x >= d) ? s[threadIdx.x - d] : 0;
        __syncthreads();
        s[threadIdx.x] += t;
        __syncthreads();
    }
    if (threadIdx.x < nb) bsum[threadIdx.x] = s[threadIdx.x] - v;
}

__global__ void k_scan3(int* __restrict__ offs, const int* __restrict__ bsum,
                        int* __restrict__ cursor, int n, int e) {
    int i = blockIdx.x * blockDim.x + threadIdx.x;
    if (i < n) {
        int v = offs[i] + bsum[i >> 8];
        offs[i] = v;
        cursor[i] = v;
    }
    if (i == 0) offs[n] = e;
}

// bucket edges by dst. nontemporal store: the 800k scattered 4B stores hit 50k
// active cursor lines from 8 XCDs -> 16x writeback amplification via L2
// partial-dirty lines (52 MB WRITE for 3.2 MB payload, round 4). NT bypasses.
__global__ void k_fill(const int* __restrict__ src, const int* __restrict__ dst,
                       int* __restrict__ cursor, int* __restrict__ ssrc, int e) {
    int i = blockIdx.x * blockDim.x + threadIdx.x;
    if (i < e) {
        int pos = atomicAdd(&cursor[dst[i]], 1);
        __builtin_nontemporal_store(src[i], &ssrc[pos]);
    }
}

// ---------------- feature kernels ----------------

// G = x * dinv[row], fp32 -> fp16
__global__ void k_scale(const float* __restrict__ x, const float* __restrict__ dinv,
                        half_t* __restrict__ G, int n) {
    int idx = blockIdx.x * blockDim.x + threadIdx.x;
    if (idx >= n * 4) return;                  // D=16 -> 4 chunks of 4
    float d = dinv[idx >> 2];
    float4 v = ((const float4*)x)[idx];
    half4 h;
    h.x = (half_t)(v.x * d); h.y = (half_t)(v.y * d);
    h.z = (half_t)(v.z * d); h.w = (half_t)(v.w * d);
    ((half4*)G)[idx] = h;
}

// A[i] = (G[i] + sum_{j in N(i)} G[src_j]) * dinv[i] — fp16 gather, fp32 accumulate
template<int D>
__global__ void __launch_bounds__(TPB)
k_gather(const int* __restrict__ offs, const int* __restrict__ ssrc,
         const half_t* __restrict__ G, const float* __restrict__ dinv,
         float* __restrict__ A, int n) {
    constexpr int C = D / 4;
    int idx = blockIdx.x * blockDim.x + threadIdx.x;
    if (idx >= n * C) return;
    int i = idx / C;
    int c = idx & (C - 1);
    const half4* Grow = (const half4*)G;
    half4 hs = Grow[(size_t)i * C + c];        // self-loop term (already *dinv[i])
    float ax = (float)hs.x, ay = (float)hs.y, az = (float)hs.z, aw = (float)hs.w;
    int s0 = offs[i], s1 = offs[i + 1];
    int j = s0;
    for (; j + 1 < s1; j += 2) {
        int sa = ssrc[j], sb = ssrc[j + 1];
        half4 ga = Grow[(size_t)sa * C + c];
        half4 gb = Grow[(size_t)sb * C + c];
        ax += (float)ga.x + (float)gb.x; ay += (float)ga.y + (float)gb.y;
        az += (float)ga.z + (float)gb.z; aw += (float)ga.w + (float)gb.w;
    }
    if (j < s1) {
        int sa = ssrc[j];
        half4 ga = Grow[(size_t)sa * C + c];
        ax += (float)ga.x; ay += (float)ga.y; az += (float)ga.z; aw += (float)ga.w;
    }
    float di = dinv[i];
    ((float4*)A)[(size_t)i * C + c] = make_float4(ax * di, ay * di, az * di, aw * di);
}

// out = relu(A @ W + b) [* dinv if SCALE], output fp32 or fp16 (next conv's G)
// __launch_bounds__(TPB,2): round-3 lesson — default 64-VGPR cap spilled
// ~2.4 KB/thread to scratch (1.8 GB HBM traffic). unroll 2 bounds live ranges.
template<int DI, int DO, int R, bool SCALE, bool OUT_HALF>
__global__ void __launch_bounds__(TPB, 2)
k_gemm(const float* __restrict__ A, const float* __restrict__ W,
       const float* __restrict__ b, const float* __restrict__ dinv,
       void* __restrict__ outp, int n) {
    constexpr int CT = DO / 4;       // threads across columns (each owns 4 cols)
    constexpr int RT = TPB / CT;     // row groups
    constexpr int TM = RT * R;       // rows per block
    constexpr int K4 = DI / 4;
    constexpr int PX = K4 + 1;       // padded pitch
    __shared__ float4 sW4[DI * CT];
    __shared__ float4 sX4[TM * PX];
    const int tid = threadIdx.x;

    const float4* Wg = (const float4*)W;
    for (int t = tid; t < DI * CT; t += TPB) sW4[t] = Wg[t];

    const int r0 = blockIdx.x * TM;
    const float4* Ag = (const float4*)A;
    for (int t = tid; t < TM * K4; t += TPB) {
        int r = t / K4, k4 = t - r * K4;
        int row = r0 + r;
        sX4[r * PX + k4] = (row < n) ? Ag[(size_t)row * K4 + k4]
                                     : make_float4(0.f, 0.f, 0.f, 0.f);
    }
    __syncthreads();

    const int c = tid & (CT - 1);
    const int rg = tid / CT;
    const int rbase = rg * R;
    float4 acc[R];
#pragma unroll
    for (int r = 0; r < R; ++r) acc[r] = make_float4(0.f, 0.f, 0.f, 0.f);

#pragma unroll 2
    for (int k4 = 0; k4 < K4; ++k4) {
        float4 xv[R];
#pragma unroll
        for (int r = 0; r < R; ++r) xv[r] = sX4[(rbase + r) * PX + k4];
#pragma unroll
        for (int kk = 0; kk < 4; ++kk) {
            float4 wv = sW4[(k4 * 4 + kk) * CT + c];
#pragma unroll
            for (int r = 0; r < R; ++r) {
                float xs = (kk == 0) ? xv[r].x : (kk == 1) ? xv[r].y
                         : (kk == 2) ? xv[r].z : xv[r].w;
                acc[r].x += xs * wv.x; acc[r].y += xs * wv.y;
                acc[r].z += xs * wv.z; acc[r].w += xs * wv.w;
            }
        }
    }

    float4 bc = ((const float4*)b)[c];
#pragma unroll
    for (int r = 0; r < R; ++r) {
        int row = r0 + rbase + r;
        if (row < n) {
            float4 o;
            o.x = fmaxf(acc[r].x + bc.x, 0.f);
            o.y = fmaxf(acc[r].y + bc.y, 0.f);
            o.z = fmaxf(acc[r].z + bc.z, 0.f);
            o.w = fmaxf(acc[r].w + bc.w, 0.f);
            if (SCALE) {
                float d = dinv[row];
                o.x *= d; o.y *= d; o.z *= d; o.w *= d;
            }
            if (OUT_HALF) {
                half4 h;
                h.x = (half_t)o.x; h.y = (half_t)o.y;
                h.z = (half_t)o.z; h.w = (half_t)o.w;
                ((half4*)outp)[(size_t)row * CT + c] = h;
            } else {
                ((float4*)outp)[(size_t)row * CT + c] = o;
            }
        }
    }
}

extern "C" void kernel_launch(void* const* d_in, const int* in_sizes, int n_in,
                              void* d_out, int out_size, void* d_ws, size_t ws_size,
                              hipStream_t stream) {
    const float* x   = (const float*)d_in[0];
    const int*   ei  = (const int*)d_in[1];
    const float* W1  = (const float*)d_in[2];
    const float* bb1 = (const float*)d_in[3];
    const float* W2  = (const float*)d_in[4];
    const float* bb2 = (const float*)d_in[5];
    const float* W3  = (const float*)d_in[6];
    const float* bb3 = (const float*)d_in[7];
    const float* Wl1 = (const float*)d_in[8];
    const float* bl1 = (const float*)d_in[9];
    const float* Wl2 = (const float*)d_in[10];
    const float* bl2 = (const float*)d_in[11];
    const float* Wl3 = (const float*)d_in[12];
    const float* bl3 = (const float*)d_in[13];
    float* out = (float*)d_out;

    const int n = in_sizes[0] / 16;   // 50000
    const int e = in_sizes[1] / 2;    // 800000
    const int* src = ei;
    const int* dst = ei + e;

    char* p = (char*)d_ws;
    auto alloc = [&](size_t bytes) {
        char* r = p;
        p += (bytes + 255) & ~(size_t)255;
        return r;
    };
    const int nb = cdiv(n, 256);
    float*  dinv   = (float*) alloc((size_t)n * 4);
    int*    cnt    = (int*)   alloc((size_t)n * 4);
    int*    offs   = (int*)   alloc((size_t)(n + 1) * 4);
    int*    cursor = (int*)   alloc((size_t)n * 4);
    int*    bsum   = (int*)   alloc(256 * 4);
    int*    ssrc   = (int*)   alloc((size_t)e * 4);
    half_t* H1     = (half_t*)alloc((size_t)n * 64 * 2);   // fp16 G (<=64 wide)
    half_t* H2     = (half_t*)alloc((size_t)n * 64 * 2);
    float*  A      = (float*) alloc((size_t)n * 64 * 4);   // gather out (<=64 wide)
    float*  X3     = (float*) alloc((size_t)n * 128 * 4);  // conv3 out
    float*  T1     = A;                                    // head temp (A dead)
    float*  T2     = (float*)H1;                           // head temp (H dead)

    // ---- CSR + dinv ----
    k_zero_int<<<cdiv(n, TPB), TPB, 0, stream>>>(cnt, n);
    k_hist<<<cdiv(e, TPB), TPB, 0, stream>>>(dst, cnt, e);
    k_scan1<<<nb, 256, 0, stream>>>(cnt, offs, bsum, dinv, n);
    k_scan2<<<1, 256, 0, stream>>>(bsum, nb);
    k_scan3<<<cdiv(n, TPB), TPB, 0, stream>>>(offs, bsum, cursor, n, e);
    k_fill<<<cdiv(e, TPB), TPB, 0, stream>>>(src, dst, cursor, ssrc, e);

    // ---- conv1: 16 -> 32 ----
    k_scale<<<cdiv(n * 4, TPB), TPB, 0, stream>>>(x, dinv, H1, n);
    k_gather<16><<<cdiv(n * 4, TPB), TPB, 0, stream>>>(offs, ssrc, H1, dinv, A, n);
    k_gemm<16, 32, 4, true, true><<<cdiv(n, 128), TPB, 0, stream>>>(A, W1, bb1, dinv, H2, n);

    // ---- conv2: 32 -> 64 ----
    k_gather<32><<<cdiv(n * 8, TPB), TPB, 0, stream>>>(offs, ssrc, H2, dinv, A, n);
    k_gemm<32, 64, 4, true, true><<<cdiv(n, 64), TPB, 0, stream>>>(A, W2, bb2, dinv, H1, n);

    // ---- conv3: 64 -> 128 ----
    k_gather<64><<<cdiv(n * 16, TPB), TPB, 0, stream>>>(offs, ssrc, H1, dinv, A, n);
    k_gemm<64, 128, 4, false, false><<<cdiv(n, 32), TPB, 0, stream>>>(A, W3, bb3, nullptr, X3, n);

    // ---- dense head: 128 -> 64 -> 32 -> 16 ----
    k_gemm<128, 64, 2, false, false><<<cdiv(n, 32), TPB, 0, stream>>>(X3, Wl1, bl1, nullptr, T1, n);
    k_gemm<64, 32, 2, false, false><<<cdiv(n, 64), TPB, 0, stream>>>(T1, Wl2, bl2, nullptr, T2, n);
    k_gemm<32, 16, 2, false, false><<<cdiv(n, 128), TPB, 0, stream>>>(T2, Wl3, bl3, nullptr, out, n);
}

// Round 6
// 231.560 us; speedup vs baseline: 6.1225x; 1.3162x over previous
//
#include <hip/hip_runtime.h>

#define TPB 256
#define TE  2048      // edges per binscatter block
#define MAXB 6144     // max edges per coarse bucket (mean 4096, sigma ~64)

typedef _Float16 half_t;
typedef _Float16 half4 __attribute__((ext_vector_type(4)));
typedef _Float16 half8 __attribute__((ext_vector_type(8)));
typedef float float8v __attribute__((ext_vector_type(8)));

static inline int cdiv(int a, int b) { return (a + b - 1) / b; }

// ---------------- CSR build: coalesced two-phase bucket sort ----------------
// Round-5 lesson: scattered 4B stores are ~16x write-amplified and NT hints
// make it WORSE (each store -> own partial-sector HBM write). All global
// writes below are contiguous runs.

__global__ void k_zero_int(int* p, int n) {
    int i = blockIdx.x * blockDim.x + threadIdx.x;
    if (i < n) p[i] = 0;
}

// coarse histogram: bucket = dst>>8 (196 buckets), LDS-staged
__global__ void k_bhist(const int* __restrict__ dst, int* __restrict__ gcnt,
                        int e, int nb) {
    __shared__ int lc[256];
    for (int t = threadIdx.x; t < nb; t += TPB) lc[t] = 0;
    __syncthreads();
    for (int i = blockIdx.x * TPB + threadIdx.x; i < e; i += gridDim.x * TPB)
        atomicAdd(&lc[dst[i] >> 8], 1);
    __syncthreads();
    for (int t = threadIdx.x; t < nb; t += TPB) {
        int v = lc[t];
        if (v) atomicAdd(&gcnt[t], v);
    }
}

// single-block exclusive scan of bucket counts -> bstart, bcur
__global__ void k_bscan(const int* __restrict__ gcnt, int* __restrict__ bstart,
                        int* __restrict__ bcur, int nb, int e) {
    __shared__ int s[256];
    int t = threadIdx.x;
    int v = (t < nb) ? gcnt[t] : 0;
    s[t] = v;
    __syncthreads();
    for (int d = 1; d < 256; d <<= 1) {
        int x = (t >= d) ? s[t - d] : 0;
        __syncthreads();
        s[t] += x;
        __syncthreads();
    }
    if (t < nb) { int ex = s[t] - v; bstart[t] = ex; bcur[t] = ex; }
    if (t == 0) bstart[nb] = e;
}

// bin edges into bucket regions; LDS multisplit -> runs of ~10 contiguous words
__global__ void __launch_bounds__(TPB)
k_binscatter(const int* __restrict__ src, const int* __restrict__ dst,
             int* __restrict__ bcur, unsigned int* __restrict__ gbuf,
             int e, int nb) {
    __shared__ int lcnt[256], loffs[256], lcur[256], gres[256];
    __shared__ int ss[256];
    __shared__ unsigned int ldata[TE];
    const int base = blockIdx.x * TE;
    const int cnt = min(TE, e - base);
    for (int t = threadIdx.x; t < nb; t += TPB) lcnt[t] = 0;
    __syncthreads();

    unsigned int myv[TE / TPB];
    int myb[TE / TPB];
#pragma unroll
    for (int k = 0; k < TE / TPB; ++k) {
        int j = threadIdx.x + k * TPB;                 // coalesced
        if (j < cnt) {
            int d = dst[base + j], s = src[base + j];
            int b = d >> 8;
            myv[k] = ((unsigned)b << 24) | ((unsigned)(d & 255) << 16) | (unsigned)s;
            myb[k] = b;
            atomicAdd(&lcnt[b], 1);
        } else myb[k] = -1;
    }
    __syncthreads();
    {   // scan lcnt -> loffs/lcur
        int t = threadIdx.x;
        int v = (t < nb) ? lcnt[t] : 0;
        ss[t] = v;
        __syncthreads();
        for (int d = 1; d < 256; d <<= 1) {
            int x = (t >= d) ? ss[t - d] : 0;
            __syncthreads();
            ss[t] += x;
            __syncthreads();
        }
        if (t < nb) { loffs[t] = ss[t] - v; lcur[t] = ss[t] - v; }
    }
    __syncthreads();
    for (int t = threadIdx.x; t < nb; t += TPB)
        if (lcnt[t]) gres[t] = atomicAdd(&bcur[t], lcnt[t]);
#pragma unroll
    for (int k = 0; k < TE / TPB; ++k) {
        if (myb[k] >= 0) {
            int p = atomicAdd(&lcur[myb[k]], 1);
            ldata[p] = myv[k];
        }
    }
    __syncthreads();
    for (int j = threadIdx.x; j < cnt; j += TPB) {     // contiguous per-bucket runs
        unsigned int v = ldata[j];
        int b = v >> 24;
        gbuf[gres[b] + (j - loffs[b])] = v & 0xFFFFFFu;
    }
}

// per-bucket exact CSR: emits offs, dinv, and fully-coalesced ssrc
__global__ void __launch_bounds__(TPB)
k_csr(const unsigned int* __restrict__ gbuf, const int* __restrict__ bstart,
      int* __restrict__ offs, float* __restrict__ dinv, int* __restrict__ ssrc,
      int n, int e) {
    __shared__ int cnt[256], loffs2[256], lcur2[256], ss[256];
    __shared__ int stage[MAXB];
    const int b = blockIdx.x;
    const int s0 = bstart[b], s1 = bstart[b + 1];
    const int m = s1 - s0;
    cnt[threadIdx.x] = 0;
    __syncthreads();
    for (int j = threadIdx.x; j < m; j += TPB)
        atomicAdd(&cnt[(gbuf[s0 + j] >> 16) & 255], 1);
    __syncthreads();
    {
        int t = threadIdx.x;
        int v = cnt[t];
        ss[t] = v;
        __syncthreads();
        for (int d = 1; d < 256; d <<= 1) {
            int x = (t >= d) ? ss[t - d] : 0;
            __syncthreads();
            ss[t] += x;
            __syncthreads();
        }
        loffs2[t] = ss[t] - v;
        lcur2[t] = ss[t] - v;
        int node = b * 256 + t;
        if (node < n) {
            offs[node] = s0 + loffs2[t];
            dinv[node] = rsqrtf((float)v + 1.0f);      // +1 self-loop
        }
    }
    __syncthreads();
    for (int j = threadIdx.x; j < m; j += TPB) {
        unsigned int v = gbuf[s0 + j];
        int p = atomicAdd(&lcur2[(v >> 16) & 255], 1);
        stage[p] = (int)(v & 0xFFFFu);
    }
    __syncthreads();
    for (int j = threadIdx.x; j < m; j += TPB) ssrc[s0 + j] = stage[j];
    if (b == 0 && threadIdx.x == 0) offs[n] = e;
}

// ---------------- feature kernels ----------------

// G = x * dinv[row], fp32 -> fp16, 8-wide (D=16 -> 2 chunks)
__global__ void k_scale(const float* __restrict__ x, const float* __restrict__ dinv,
                        half_t* __restrict__ G, int n) {
    int idx = blockIdx.x * blockDim.x + threadIdx.x;
    if (idx >= n * 2) return;
    float d = dinv[idx >> 1];
    float8v v = ((const float8v*)x)[idx];
    half8 h;
#pragma unroll
    for (int q = 0; q < 8; ++q) h[q] = (half_t)(v[q] * d);
    ((half8*)G)[idx] = h;
}

// A[i] = (G[i] + sum_{j in N(i)} G[src_j]) * dinv[i] — fp16 half8 gather, fp32 acc
template<int D>
__global__ void __launch_bounds__(TPB)
k_gather(const int* __restrict__ offs, const int* __restrict__ ssrc,
         const half_t* __restrict__ G, const float* __restrict__ dinv,
         float* __restrict__ A, int n) {
    constexpr int C = D / 8;
    int idx = blockIdx.x * blockDim.x + threadIdx.x;
    if (idx >= n * C) return;
    int i = idx / C;
    int c = idx & (C - 1);
    const half8* Grow = (const half8*)G;
    half8 hs = Grow[(size_t)i * C + c];        // self-loop (already *dinv[i])
    float8v acc;
#pragma unroll
    for (int q = 0; q < 8; ++q) acc[q] = (float)hs[q];
    int s0 = offs[i], s1 = offs[i + 1];
    int j = s0;
    for (; j + 1 < s1; j += 2) {
        int sa = ssrc[j], sb = ssrc[j + 1];
        half8 ga = Grow[(size_t)sa * C + c];
        half8 gb = Grow[(size_t)sb * C + c];
#pragma unroll
        for (int q = 0; q < 8; ++q) acc[q] += (float)ga[q] + (float)gb[q];
    }
    if (j < s1) {
        half8 ga = Grow[(size_t)ssrc[j] * C + c];
#pragma unroll
        for (int q = 0; q < 8; ++q) acc[q] += (float)ga[q];
    }
    float di = dinv[i];
#pragma unroll
    for (int q = 0; q < 8; ++q) acc[q] *= di;
    ((float8v*)A)[(size_t)i * C + c] = acc;
}

// out = relu(A @ W + b) [* dinv if SCALE], output fp32 or fp16
// __launch_bounds__(TPB,2): round-3 lesson — default 64-VGPR cap spilled
// ~2.4 KB/thread to scratch (1.8 GB HBM traffic). unroll 2 bounds live ranges.
template<int DI, int DO, int R, bool SCALE, bool OUT_HALF>
__global__ void __launch_bounds__(TPB, 2)
k_gemm(const float* __restrict__ A, const float* __restrict__ W,
       const float* __restrict__ b, const float* __restrict__ dinv,
       void* __restrict__ outp, int n) {
    constexpr int CT = DO / 4;
    constexpr int RT = TPB / CT;
    constexpr int TM = RT * R;
    constexpr int K4 = DI / 4;
    constexpr int PX = K4 + 1;
    __shared__ float4 sW4[DI * CT];
    __shared__ float4 sX4[TM * PX];
    const int tid = threadIdx.x;

    const float4* Wg = (const float4*)W;
    for (int t = tid; t < DI * CT; t += TPB) sW4[t] = Wg[t];

    const int r0 = blockIdx.x * TM;
    const float4* Ag = (const float4*)A;
    for (int t = tid; t < TM * K4; t += TPB) {
        int r = t / K4, k4 = t - r * K4;
        int row = r0 + r;
        sX4[r * PX + k4] = (row < n) ? Ag[(size_t)row * K4 + k4]
                                     : make_float4(0.f, 0.f, 0.f, 0.f);
    }
    __syncthreads();

    const int c = tid & (CT - 1);
    const int rg = tid / CT;
    const int rbase = rg * R;
    float4 acc[R];
#pragma unroll
    for (int r = 0; r < R; ++r) acc[r] = make_float4(0.f, 0.f, 0.f, 0.f);

#pragma unroll 2
    for (int k4 = 0; k4 < K4; ++k4) {
        float4 xv[R];
#pragma unroll
        for (int r = 0; r < R; ++r) xv[r] = sX4[(rbase + r) * PX + k4];
#pragma unroll
        for (int kk = 0; kk < 4; ++kk) {
            float4 wv = sW4[(k4 * 4 + kk) * CT + c];
#pragma unroll
            for (int r = 0; r < R; ++r) {
                float xs = (kk == 0) ? xv[r].x : (kk == 1) ? xv[r].y
                         : (kk == 2) ? xv[r].z : xv[r].w;
                acc[r].x += xs * wv.x; acc[r].y += xs * wv.y;
                acc[r].z += xs * wv.z; acc[r].w += xs * wv.w;
            }
        }
    }

    float4 bc = ((const float4*)b)[c];
#pragma unroll
    for (int r = 0; r < R; ++r) {
        int row = r0 + rbase + r;
        if (row < n) {
            float4 o;
            o.x = fmaxf(acc[r].x + bc.x, 0.f);
            o.y = fmaxf(acc[r].y + bc.y, 0.f);
            o.z = fmaxf(acc[r].z + bc.z, 0.f);
            o.w = fmaxf(acc[r].w + bc.w, 0.f);
            if (SCALE) {
                float d = dinv[row];
                o.x *= d; o.y *= d; o.z *= d; o.w *= d;
            }
            if (OUT_HALF) {
                half4 h;
                h.x = (half_t)o.x; h.y = (half_t)o.y;
                h.z = (half_t)o.z; h.w = (half_t)o.w;
                ((half4*)outp)[(size_t)row * CT + c] = h;
            } else {
                ((float4*)outp)[(size_t)row * CT + c] = o;
            }
        }
    }
}

extern "C" void kernel_launch(void* const* d_in, const int* in_sizes, int n_in,
                              void* d_out, int out_size, void* d_ws, size_t ws_size,
                              hipStream_t stream) {
    const float* x   = (const float*)d_in[0];
    const int*   ei  = (const int*)d_in[1];
    const float* W1  = (const float*)d_in[2];
    const float* bb1 = (const float*)d_in[3];
    const float* W2  = (const float*)d_in[4];
    const float* bb2 = (const float*)d_in[5];
    const float* W3  = (const float*)d_in[6];
    const float* bb3 = (const float*)d_in[7];
    const float* Wl1 = (const float*)d_in[8];
    const float* bl1 = (const float*)d_in[9];
    const float* Wl2 = (const float*)d_in[10];
    const float* bl2 = (const float*)d_in[11];
    const float* Wl3 = (const float*)d_in[12];
    const float* bl3 = (const float*)d_in[13];
    float* out = (float*)d_out;

    const int n = in_sizes[0] / 16;   // 50000
    const int e = in_sizes[1] / 2;    // 800000
    const int* src = ei;
    const int* dst = ei + e;
    const int nb = cdiv(n, 256);      // 196 coarse buckets

    char* p = (char*)d_ws;
    auto alloc = [&](size_t bytes) {
        char* r = p;
        p += (bytes + 255) & ~(size_t)255;
        return r;
    };
    float*        dinv   = (float*)        alloc((size_t)n * 4);
    int*          offs   = (int*)          alloc((size_t)(n + 1) * 4);
    int*          gcnt   = (int*)          alloc(256 * 4);
    int*          bstart = (int*)          alloc(257 * 4);
    int*          bcur   = (int*)          alloc(256 * 4);
    unsigned int* gbuf   = (unsigned int*) alloc((size_t)e * 4);
    int*          ssrc   = (int*)          alloc((size_t)e * 4);
    half_t*       H1     = (half_t*)       alloc((size_t)n * 64 * 2);
    half_t*       H2     = (half_t*)       alloc((size_t)n * 64 * 2);
    float*        A      = (float*)        alloc((size_t)n * 64 * 4);
    float*        X3     = (float*)        alloc((size_t)n * 128 * 4);
    float*        T1     = A;
    float*        T2     = (float*)H1;

    // ---- CSR + dinv (all-coalesced bucket sort) ----
    k_zero_int<<<1, 256, 0, stream>>>(gcnt, nb);
    k_bhist<<<512, TPB, 0, stream>>>(dst, gcnt, e, nb);
    k_bscan<<<1, 256, 0, stream>>>(gcnt, bstart, bcur, nb, e);
    k_binscatter<<<cdiv(e, TE), TPB, 0, stream>>>(src, dst, bcur, gbuf, e, nb);
    k_csr<<<nb, TPB, 0, stream>>>(gbuf, bstart, offs, dinv, ssrc, n, e);

    // ---- conv1: 16 -> 32 ----
    k_scale<<<cdiv(n * 2, TPB), TPB, 0, stream>>>(x, dinv, H1, n);
    k_gather<16><<<cdiv(n * 2, TPB), TPB, 0, stream>>>(offs, ssrc, H1, dinv, A, n);
    k_gemm<16, 32, 4, true, true><<<cdiv(n, 128), TPB, 0, stream>>>(A, W1, bb1, dinv, H2, n);

    // ---- conv2: 32 -> 64 ----
    k_gather<32><<<cdiv(n * 4, TPB), TPB, 0, stream>>>(offs, ssrc, H2, dinv, A, n);
    k_gemm<32, 64, 4, true, true><<<cdiv(n, 64), TPB, 0, stream>>>(A, W2, bb2, dinv, H1, n);

    // ---- conv3: 64 -> 128 ----
    k_gather<64><<<cdiv(n * 8, TPB), TPB, 0, stream>>>(offs, ssrc, H1, dinv, A, n);
    k_gemm<64, 128, 4, false, false><<<cdiv(n, 32), TPB, 0, stream>>>(A, W3, bb3, nullptr, X3, n);

    // ---- dense head: 128 -> 64 -> 32 -> 16 ----
    k_gemm<128, 64, 2, false, false><<<cdiv(n, 32), TPB, 0, stream>>>(X3, Wl1, bl1, nullptr, T1, n);
    k_gemm<64, 32, 2, false, false><<<cdiv(n, 64), TPB, 0, stream>>>(T1, Wl2, bl2, nullptr, T2, n);
    k_gemm<32, 16, 2, false, false><<<cdiv(n, 128), TPB, 0, stream>>>(T2, Wl3, bl3, nullptr, out, n);
}

// Round 7
// 230.757 us; speedup vs baseline: 6.1438x; 1.0035x over previous
//
#include <hip/hip_runtime.h>

#define TPB 256
#define TE  2048      // edges per binscatter block
#define MAXB 6144     // max edges per coarse bucket (mean 4096, sigma ~64)

typedef _Float16 half_t;
typedef _Float16 half4 __attribute__((ext_vector_type(4)));
typedef _Float16 half8 __attribute__((ext_vector_type(8)));
typedef float float8v __attribute__((ext_vector_type(8)));

static inline int cdiv(int a, int b) { return (a + b - 1) / b; }

// ---------------- CSR build: coalesced two-phase bucket sort ----------------
// Round-5 lesson: scattered 4B stores are ~16x write-amplified; NT hints make
// it worse. All global writes below are contiguous runs.

__global__ void k_zero_int(int* p, int n) {
    int i = blockIdx.x * blockDim.x + threadIdx.x;
    if (i < n) p[i] = 0;
}

__global__ void k_bhist(const int* __restrict__ dst, int* __restrict__ gcnt,
                        int e, int nb) {
    __shared__ int lc[256];
    for (int t = threadIdx.x; t < nb; t += TPB) lc[t] = 0;
    __syncthreads();
    for (int i = blockIdx.x * TPB + threadIdx.x; i < e; i += gridDim.x * TPB)
        atomicAdd(&lc[dst[i] >> 8], 1);
    __syncthreads();
    for (int t = threadIdx.x; t < nb; t += TPB) {
        int v = lc[t];
        if (v) atomicAdd(&gcnt[t], v);
    }
}

__global__ void k_bscan(const int* __restrict__ gcnt, int* __restrict__ bstart,
                        int* __restrict__ bcur, int nb, int e) {
    __shared__ int s[256];
    int t = threadIdx.x;
    int v = (t < nb) ? gcnt[t] : 0;
    s[t] = v;
    __syncthreads();
    for (int d = 1; d < 256; d <<= 1) {
        int x = (t >= d) ? s[t - d] : 0;
        __syncthreads();
        s[t] += x;
        __syncthreads();
    }
    if (t < nb) { int ex = s[t] - v; bstart[t] = ex; bcur[t] = ex; }
    if (t == 0) bstart[nb] = e;
}

__global__ void __launch_bounds__(TPB)
k_binscatter(const int* __restrict__ src, const int* __restrict__ dst,
             int* __restrict__ bcur, unsigned int* __restrict__ gbuf,
             int e, int nb) {
    __shared__ int lcnt[256], loffs[256], lcur[256], gres[256];
    __shared__ int ss[256];
    __shared__ unsigned int ldata[TE];
    const int base = blockIdx.x * TE;
    const int cnt = min(TE, e - base);
    for (int t = threadIdx.x; t < nb; t += TPB) lcnt[t] = 0;
    __syncthreads();

    unsigned int myv[TE / TPB];
    int myb[TE / TPB];
#pragma unroll
    for (int k = 0; k < TE / TPB; ++k) {
        int j = threadIdx.x + k * TPB;
        if (j < cnt) {
            int d = dst[base + j], s = src[base + j];
            int b = d >> 8;
            myv[k] = ((unsigned)b << 24) | ((unsigned)(d & 255) << 16) | (unsigned)s;
            myb[k] = b;
            atomicAdd(&lcnt[b], 1);
        } else myb[k] = -1;
    }
    __syncthreads();
    {
        int t = threadIdx.x;
        int v = (t < nb) ? lcnt[t] : 0;
        ss[t] = v;
        __syncthreads();
        for (int d = 1; d < 256; d <<= 1) {
            int x = (t >= d) ? ss[t - d] : 0;
            __syncthreads();
            ss[t] += x;
            __syncthreads();
        }
        if (t < nb) { loffs[t] = ss[t] - v; lcur[t] = ss[t] - v; }
    }
    __syncthreads();
    for (int t = threadIdx.x; t < nb; t += TPB)
        if (lcnt[t]) gres[t] = atomicAdd(&bcur[t], lcnt[t]);
#pragma unroll
    for (int k = 0; k < TE / TPB; ++k) {
        if (myb[k] >= 0) {
            int p = atomicAdd(&lcur[myb[k]], 1);
            ldata[p] = myv[k];
        }
    }
    __syncthreads();
    for (int j = threadIdx.x; j < cnt; j += TPB) {
        unsigned int v = ldata[j];
        int b = v >> 24;
        gbuf[gres[b] + (j - loffs[b])] = v & 0xFFFFFFu;
    }
}

__global__ void __launch_bounds__(TPB)
k_csr(const unsigned int* __restrict__ gbuf, const int* __restrict__ bstart,
      int* __restrict__ offs, float* __restrict__ dinv, int* __restrict__ ssrc,
      int n, int e) {
    __shared__ int cnt[256], loffs2[256], lcur2[256], ss[256];
    __shared__ int stage[MAXB];
    const int b = blockIdx.x;
    const int s0 = bstart[b], s1 = bstart[b + 1];
    const int m = s1 - s0;
    cnt[threadIdx.x] = 0;
    __syncthreads();
    for (int j = threadIdx.x; j < m; j += TPB)
        atomicAdd(&cnt[(gbuf[s0 + j] >> 16) & 255], 1);
    __syncthreads();
    {
        int t = threadIdx.x;
        int v = cnt[t];
        ss[t] = v;
        __syncthreads();
        for (int d = 1; d < 256; d <<= 1) {
            int x = (t >= d) ? ss[t - d] : 0;
            __syncthreads();
            ss[t] += x;
            __syncthreads();
        }
        loffs2[t] = ss[t] - v;
        lcur2[t] = ss[t] - v;
        int node = b * 256 + t;
        if (node < n) {
            offs[node] = s0 + loffs2[t];
            dinv[node] = rsqrtf((float)v + 1.0f);
        }
    }
    __syncthreads();
    for (int j = threadIdx.x; j < m; j += TPB) {
        unsigned int v = gbuf[s0 + j];
        int p = atomicAdd(&lcur2[(v >> 16) & 255], 1);
        stage[p] = (int)(v & 0xFFFFu);
    }
    __syncthreads();
    for (int j = threadIdx.x; j < m; j += TPB) ssrc[s0 + j] = stage[j];
    if (b == 0 && threadIdx.x == 0) offs[n] = e;
}

// ---------------- feature kernels ----------------

// G = x * dinv[row], fp32 -> fp16, half8-wide (D=16 -> 2 chunks)
__global__ void k_scale(const float* __restrict__ x, const float* __restrict__ dinv,
                        half_t* __restrict__ G, int n) {
    int idx = blockIdx.x * blockDim.x + threadIdx.x;
    if (idx >= n * 2) return;
    float d = dinv[idx >> 1];
    float8v v = ((const float8v*)x)[idx];
    half8 h;
#pragma unroll
    for (int q = 0; q < 8; ++q) h[q] = (half_t)(v[q] * d);
    ((half8*)G)[idx] = h;
}

// Fused gather + GEMM conv layer:
//   tile = (G[i] + sum_{j in N(i)} G[src_j]) * dinv[i]  -> LDS
//   out  = relu(tile @ W + b) [* dinv if SCALE], fp16 or fp32 out
// Thread mapping identity: TM*C == TPB for all three convs.
// __launch_bounds__(TPB,2): round-3 lesson (64-VGPR default cap spilled 2.4KB/thread).
template<int DI, int DO, int R, bool SCALE, bool OUT_HALF>
__global__ void __launch_bounds__(TPB, 2)
k_conv(const int* __restrict__ offs, const int* __restrict__ ssrc,
       const half_t* __restrict__ G, const float* __restrict__ dinv,
       const float* __restrict__ W, const float* __restrict__ b,
       void* __restrict__ outp, int n) {
    constexpr int CT = DO / 4;
    constexpr int RT = TPB / CT;
    constexpr int TM = RT * R;
    constexpr int K4 = DI / 4;
    constexpr int PX = K4 + 1;
    constexpr int C  = DI / 8;
    static_assert(TM * C == TPB, "gather/gemm tile mismatch");
    __shared__ float4 sW4[DI * CT];
    __shared__ float4 sX4[TM * PX];
    const int tid = threadIdx.x;
    const int r0 = blockIdx.x * TM;

    const float4* Wg = (const float4*)W;
    for (int t = tid; t < DI * CT; t += TPB) sW4[t] = Wg[t];

    // ---- gather phase: each thread aggregates one half8 chunk of one row ----
    {
        int gr = tid / C;
        int gc = tid - gr * C;
        int row = r0 + gr;
        float8v acc;
#pragma unroll
        for (int q = 0; q < 8; ++q) acc[q] = 0.f;
        if (row < n) {
            const half8* Grow = (const half8*)G;
            half8 hs = Grow[(size_t)row * C + gc];
#pragma unroll
            for (int q = 0; q < 8; ++q) acc[q] = (float)hs[q];
            int s0 = offs[row], s1 = offs[row + 1];
            int j = s0;
            for (; j + 1 < s1; j += 2) {
                int sa = ssrc[j], sb = ssrc[j + 1];
                half8 ga = Grow[(size_t)sa * C + gc];
                half8 gb = Grow[(size_t)sb * C + gc];
#pragma unroll
                for (int q = 0; q < 8; ++q) acc[q] += (float)ga[q] + (float)gb[q];
            }
            if (j < s1) {
                half8 ga = Grow[(size_t)ssrc[j] * C + gc];
#pragma unroll
                for (int q = 0; q < 8; ++q) acc[q] += (float)ga[q];
            }
            float di = dinv[row];
#pragma unroll
            for (int q = 0; q < 8; ++q) acc[q] *= di;
        }
        sX4[gr * PX + 2 * gc]     = make_float4(acc[0], acc[1], acc[2], acc[3]);
        sX4[gr * PX + 2 * gc + 1] = make_float4(acc[4], acc[5], acc[6], acc[7]);
    }
    __syncthreads();

    // ---- GEMM phase ----
    const int c = tid & (CT - 1);
    const int rg = tid / CT;
    const int rbase = rg * R;
    float4 acc[R];
#pragma unroll
    for (int r = 0; r < R; ++r) acc[r] = make_float4(0.f, 0.f, 0.f, 0.f);

#pragma unroll 2
    for (int k4 = 0; k4 < K4; ++k4) {
        float4 xv[R];
#pragma unroll
        for (int r = 0; r < R; ++r) xv[r] = sX4[(rbase + r) * PX + k4];
#pragma unroll
        for (int kk = 0; kk < 4; ++kk) {
            float4 wv = sW4[(k4 * 4 + kk) * CT + c];
#pragma unroll
            for (int r = 0; r < R; ++r) {
                float xs = (kk == 0) ? xv[r].x : (kk == 1) ? xv[r].y
                         : (kk == 2) ? xv[r].z : xv[r].w;
                acc[r].x += xs * wv.x; acc[r].y += xs * wv.y;
                acc[r].z += xs * wv.z; acc[r].w += xs * wv.w;
            }
        }
    }

    float4 bc = ((const float4*)b)[c];
#pragma unroll
    for (int r = 0; r < R; ++r) {
        int row = r0 + rbase + r;
        if (row < n) {
            float4 o;
            o.x = fmaxf(acc[r].x + bc.x, 0.f);
            o.y = fmaxf(acc[r].y + bc.y, 0.f);
            o.z = fmaxf(acc[r].z + bc.z, 0.f);
            o.w = fmaxf(acc[r].w + bc.w, 0.f);
            if (SCALE) {
                float d = dinv[row];
                o.x *= d; o.y *= d; o.z *= d; o.w *= d;
            }
            if (OUT_HALF) {
                half4 h;
                h.x = (half_t)o.x; h.y = (half_t)o.y;
                h.z = (half_t)o.z; h.w = (half_t)o.w;
                ((half4*)outp)[(size_t)row * CT + c] = h;
            } else {
                ((float4*)outp)[(size_t)row * CT + c] = o;
            }
        }
    }
}

// Fused dense head: out = relu(relu(relu(X@W1+b1)@W2+b2)@W3+b3)
// 64 rows/block, weights fp16 in LDS, staged h1/h2 tiles in padded LDS.
__global__ void __launch_bounds__(256, 2)
k_head(const half_t* __restrict__ X,
       const float* __restrict__ W1, const float* __restrict__ b1,
       const float* __restrict__ W2, const float* __restrict__ b2,
       const float* __restrict__ W3, const float* __restrict__ b3,
       float* __restrict__ out, int n) {
    __shared__ half_t hW1[128 * 64];
    __shared__ half_t hW2[64 * 32];
    __shared__ half_t hW3[32 * 16];
    __shared__ float h1[64 * 65];
    __shared__ float h2[64 * 33];
    const int tid = threadIdx.x;
    const int r0 = blockIdx.x * 64;

    for (int t = tid; t < 128 * 64; t += 256) hW1[t] = (half_t)W1[t];
    for (int t = tid; t < 64 * 32; t += 256) hW2[t] = (half_t)W2[t];
    for (int t = tid; t < 32 * 16; t += 256) hW3[t] = (half_t)W3[t];
    __syncthreads();

    // ---- stage 1: 128 -> 64 (4 rows x 4 cols per thread) ----
    {
        const int c4 = tid & 15;          // float4 col of 64
        const int rowg = tid >> 4;        // 0..15 -> rows rowg*4..+3
        const half8* Xr = (const half8*)X;
        float acc[4][4];
#pragma unroll
        for (int r = 0; r < 4; ++r)
#pragma unroll
            for (int j = 0; j < 4; ++j) acc[r][j] = 0.f;
        for (int k8 = 0; k8 < 16; ++k8) {
            half8 xh[4];
#pragma unroll
            for (int r = 0; r < 4; ++r) {
                int row = r0 + rowg * 4 + r;
                if (row < n) xh[r] = Xr[(size_t)row * 16 + k8];
                else { half8 z; for (int q = 0; q < 8; ++q) z[q] = (half_t)0.f; xh[r] = z; }
            }
#pragma unroll
            for (int q = 0; q < 8; ++q) {
                int k = k8 * 8 + q;
                half4 w = *(const half4*)&hW1[k * 64 + c4 * 4];
                float w0 = (float)w.x, w1 = (float)w.y, w2 = (float)w.z, w3 = (float)w.w;
#pragma unroll
                for (int r = 0; r < 4; ++r) {
                    float xs = (float)xh[r][q];
                    acc[r][0] += xs * w0; acc[r][1] += xs * w1;
                    acc[r][2] += xs * w2; acc[r][3] += xs * w3;
                }
            }
        }
        float4 bc = ((const float4*)b1)[c4];
#pragma unroll
        for (int r = 0; r < 4; ++r) {
            int rl = rowg * 4 + r;
            h1[rl * 65 + c4 * 4 + 0] = fmaxf(acc[r][0] + bc.x, 0.f);
            h1[rl * 65 + c4 * 4 + 1] = fmaxf(acc[r][1] + bc.y, 0.f);
            h1[rl * 65 + c4 * 4 + 2] = fmaxf(acc[r][2] + bc.z, 0.f);
            h1[rl * 65 + c4 * 4 + 3] = fmaxf(acc[r][3] + bc.w, 0.f);
        }
    }
    __syncthreads();

    // ---- stage 2: 64 -> 32 (2 rows x 4 cols per thread) ----
    {
        const int c4 = tid & 7;
        const int rowg = tid >> 3;        // 0..31 -> rows rowg*2..+1
        float acc[2][4];
#pragma unroll
        for (int r = 0; r < 2; ++r)
#pragma unroll
            for (int j = 0; j < 4; ++j) acc[r][j] = 0.f;
#pragma unroll 4
        for (int k = 0; k < 64; ++k) {
            half4 w = *(const half4*)&hW2[k * 32 + c4 * 4];
            float w0 = (float)w.x, w1 = (float)w.y, w2 = (float)w.z, w3 = (float)w.w;
#pragma unroll
            for (int r = 0; r < 2; ++r) {
                float xs = h1[(rowg * 2 + r) * 65 + k];
                acc[r][0] += xs * w0; acc[r][1] += xs * w1;
                acc[r][2] += xs * w2; acc[r][3] += xs * w3;
            }
        }
        float4 bc = ((const float4*)b2)[c4];
#pragma unroll
        for (int r = 0; r < 2; ++r) {
            int rl = rowg * 2 + r;
            h2[rl * 33 + c4 * 4 + 0] = fmaxf(acc[r][0] + bc.x, 0.f);
            h2[rl * 33 + c4 * 4 + 1] = fmaxf(acc[r][1] + bc.y, 0.f);
            h2[rl * 33 + c4 * 4 + 2] = fmaxf(acc[r][2] + bc.z, 0.f);
            h2[rl * 33 + c4 * 4 + 3] = fmaxf(acc[r][3] + bc.w, 0.f);
        }
    }
    __syncthreads();

    // ---- stage 3: 32 -> 16 (1 row x 4 cols per thread) ----
    {
        const int c4 = tid & 3;
        const int rl = tid >> 2;          // 0..63
        float a0 = 0.f, a1 = 0.f, a2 = 0.f, a3 = 0.f;
#pragma unroll 4
        for (int k = 0; k < 32; ++k) {
            half4 w = *(const half4*)&hW3[k * 16 + c4 * 4];
            float xs = h2[rl * 33 + k];
            a0 += xs * (float)w.x; a1 += xs * (float)w.y;
            a2 += xs * (float)w.z; a3 += xs * (float)w.w;
        }
        int row = r0 + rl;
        if (row < n) {
            float4 bc = ((const float4*)b3)[c4];
            float4 o;
            o.x = fmaxf(a0 + bc.x, 0.f);
            o.y = fmaxf(a1 + bc.y, 0.f);
            o.z = fmaxf(a2 + bc.z, 0.f);
            o.w = fmaxf(a3 + bc.w, 0.f);
            ((float4*)out)[(size_t)row * 4 + c4] = o;
        }
    }
}

extern "C" void kernel_launch(void* const* d_in, const int* in_sizes, int n_in,
                              void* d_out, int out_size, void* d_ws, size_t ws_size,
                              hipStream_t stream) {
    const float* x   = (const float*)d_in[0];
    const int*   ei  = (const int*)d_in[1];
    const float* W1  = (const float*)d_in[2];
    const float* bb1 = (const float*)d_in[3];
    const float* W2  = (const float*)d_in[4];
    const float* bb2 = (const float*)d_in[5];
    const float* W3  = (const float*)d_in[6];
    const float* bb3 = (const float*)d_in[7];
    const float* Wl1 = (const float*)d_in[8];
    const float* bl1 = (const float*)d_in[9];
    const float* Wl2 = (const float*)d_in[10];
    const float* bl2 = (const float*)d_in[11];
    const float* Wl3 = (const float*)d_in[12];
    const float* bl3 = (const float*)d_in[13];
    float* out = (float*)d_out;

    const int n = in_sizes[0] / 16;   // 50000
    const int e = in_sizes[1] / 2;    // 800000
    const int* src = ei;
    const int* dst = ei + e;
    const int nb = cdiv(n, 256);      // 196 coarse buckets

    char* p = (char*)d_ws;
    auto alloc = [&](size_t bytes) {
        char* r = p;
        p += (bytes + 255) & ~(size_t)255;
        return r;
    };
    float*        dinv   = (float*)        alloc((size_t)n * 4);
    int*          offs   = (int*)          alloc((size_t)(n + 1) * 4);
    int*          gcnt   = (int*)          alloc(256 * 4);
    int*          bstart = (int*)          alloc(257 * 4);
    int*          bcur   = (int*)          alloc(256 * 4);
    unsigned int* gbuf   = (unsigned int*) alloc((size_t)e * 4);
    int*          ssrc   = (int*)          alloc((size_t)e * 4);
    half_t*       H1     = (half_t*)       alloc((size_t)n * 64 * 2);
    half_t*       H2     = (half_t*)       alloc((size_t)n * 32 * 2);
    half_t*       X3h    = (half_t*)       alloc((size_t)n * 128 * 2);

    // ---- CSR + dinv (all-coalesced bucket sort) ----
    k_zero_int<<<1, 256, 0, stream>>>(gcnt, nb);
    k_bhist<<<512, TPB, 0, stream>>>(dst, gcnt, e, nb);
    k_bscan<<<1, 256, 0, stream>>>(gcnt, bstart, bcur, nb, e);
    k_binscatter<<<cdiv(e, TE), TPB, 0, stream>>>(src, dst, bcur, gbuf, e, nb);
    k_csr<<<nb, TPB, 0, stream>>>(gbuf, bstart, offs, dinv, ssrc, n, e);

    // ---- convs (fused gather+GEMM) ----
    k_scale<<<cdiv(n * 2, TPB), TPB, 0, stream>>>(x, dinv, H1, n);
    k_conv<16, 32, 4, true, true><<<cdiv(n, 128), TPB, 0, stream>>>(
        offs, ssrc, H1, dinv, W1, bb1, H2, n);
    k_conv<32, 64, 4, true, true><<<cdiv(n, 64), TPB, 0, stream>>>(
        offs, ssrc, H2, dinv, W2, bb2, H1, n);
    k_conv<64, 128, 4, false, true><<<cdiv(n, 32), TPB, 0, stream>>>(
        offs, ssrc, H1, dinv, W3, bb3, X3h, n);

    // ---- fused dense head ----
    k_head<<<cdiv(n, 64), 256, 0, stream>>>(X3h, Wl1, bl1, Wl2, bl2, Wl3, bl3, out, n);
}

// Round 8
// 219.600 us; speedup vs baseline: 6.4559x; 1.0508x over previous
//
#include <hip/hip_runtime.h>

#define TPB 256
#define TE  2048      // edges per binscatter block
#define MAXB 6144     // max edges per coarse bucket (mean 4096, sigma ~64)

typedef _Float16 half_t;
typedef _Float16 half4 __attribute__((ext_vector_type(4)));
typedef _Float16 half8 __attribute__((ext_vector_type(8)));
typedef float float8v __attribute__((ext_vector_type(8)));

static inline int cdiv(int a, int b) { return (a + b - 1) / b; }

// ---------------- CSR build: coalesced two-phase bucket sort ----------------
// Round-5 lesson: scattered 4B stores are ~16x write-amplified; NT hints make
// it worse. All global writes below are contiguous runs.

__global__ void k_zero_int(int* p, int n) {
    int i = blockIdx.x * blockDim.x + threadIdx.x;
    if (i < n) p[i] = 0;
}

__global__ void k_bhist(const int* __restrict__ dst, int* __restrict__ gcnt,
                        int e, int nb) {
    __shared__ int lc[256];
    for (int t = threadIdx.x; t < nb; t += TPB) lc[t] = 0;
    __syncthreads();
    for (int i = blockIdx.x * TPB + threadIdx.x; i < e; i += gridDim.x * TPB)
        atomicAdd(&lc[dst[i] >> 8], 1);
    __syncthreads();
    for (int t = threadIdx.x; t < nb; t += TPB) {
        int v = lc[t];
        if (v) atomicAdd(&gcnt[t], v);
    }
}

__global__ void k_bscan(const int* __restrict__ gcnt, int* __restrict__ bstart,
                        int* __restrict__ bcur, int nb, int e) {
    __shared__ int s[256];
    int t = threadIdx.x;
    int v = (t < nb) ? gcnt[t] : 0;
    s[t] = v;
    __syncthreads();
    for (int d = 1; d < 256; d <<= 1) {
        int x = (t >= d) ? s[t - d] : 0;
        __syncthreads();
        s[t] += x;
        __syncthreads();
    }
    if (t < nb) { int ex = s[t] - v; bstart[t] = ex; bcur[t] = ex; }
    if (t == 0) bstart[nb] = e;
}

__global__ void __launch_bounds__(TPB)
k_binscatter(const int* __restrict__ src, const int* __restrict__ dst,
             int* __restrict__ bcur, unsigned int* __restrict__ gbuf,
             int e, int nb) {
    __shared__ int lcnt[256], loffs[256], lcur[256], gres[256];
    __shared__ int ss[256];
    __shared__ unsigned int ldata[TE];
    const int base = blockIdx.x * TE;
    const int cnt = min(TE, e - base);
    for (int t = threadIdx.x; t < nb; t += TPB) lcnt[t] = 0;
    __syncthreads();

    unsigned int myv[TE / TPB];
    int myb[TE / TPB];
#pragma unroll
    for (int k = 0; k < TE / TPB; ++k) {
        int j = threadIdx.x + k * TPB;
        if (j < cnt) {
            int d = dst[base + j], s = src[base + j];
            int b = d >> 8;
            myv[k] = ((unsigned)b << 24) | ((unsigned)(d & 255) << 16) | (unsigned)s;
            myb[k] = b;
            atomicAdd(&lcnt[b], 1);
        } else myb[k] = -1;
    }
    __syncthreads();
    {
        int t = threadIdx.x;
        int v = (t < nb) ? lcnt[t] : 0;
        ss[t] = v;
        __syncthreads();
        for (int d = 1; d < 256; d <<= 1) {
            int x = (t >= d) ? ss[t - d] : 0;
            __syncthreads();
            ss[t] += x;
            __syncthreads();
        }
        if (t < nb) { loffs[t] = ss[t] - v; lcur[t] = ss[t] - v; }
    }
    __syncthreads();
    for (int t = threadIdx.x; t < nb; t += TPB)
        if (lcnt[t]) gres[t] = atomicAdd(&bcur[t], lcnt[t]);
#pragma unroll
    for (int k = 0; k < TE / TPB; ++k) {
        if (myb[k] >= 0) {
            int p = atomicAdd(&lcur[myb[k]], 1);
            ldata[p] = myv[k];
        }
    }
    __syncthreads();
    for (int j = threadIdx.x; j < cnt; j += TPB) {
        unsigned int v = ldata[j];
        int b = v >> 24;
        gbuf[gres[b] + (j - loffs[b])] = v & 0xFFFFFFu;
    }
}

__global__ void __launch_bounds__(TPB)
k_csr(const unsigned int* __restrict__ gbuf, const int* __restrict__ bstart,
      int* __restrict__ offs, float* __restrict__ dinv, int* __restrict__ ssrc,
      int n, int e) {
    __shared__ int cnt[256], loffs2[256], lcur2[256], ss[256];
    __shared__ int stage[MAXB];
    const int b = blockIdx.x;
    const int s0 = bstart[b], s1 = bstart[b + 1];
    const int m = s1 - s0;
    cnt[threadIdx.x] = 0;
    __syncthreads();
    for (int j = threadIdx.x; j < m; j += TPB)
        atomicAdd(&cnt[(gbuf[s0 + j] >> 16) & 255], 1);
    __syncthreads();
    {
        int t = threadIdx.x;
        int v = cnt[t];
        ss[t] = v;
        __syncthreads();
        for (int d = 1; d < 256; d <<= 1) {
            int x = (t >= d) ? ss[t - d] : 0;
            __syncthreads();
            ss[t] += x;
            __syncthreads();
        }
        loffs2[t] = ss[t] - v;
        lcur2[t] = ss[t] - v;
        int node = b * 256 + t;
        if (node < n) {
            offs[node] = s0 + loffs2[t];
            dinv[node] = rsqrtf((float)v + 1.0f);
        }
    }
    __syncthreads();
    for (int j = threadIdx.x; j < m; j += TPB) {
        unsigned int v = gbuf[s0 + j];
        int p = atomicAdd(&lcur2[(v >> 16) & 255], 1);
        stage[p] = (int)(v & 0xFFFFu);
    }
    __syncthreads();
    for (int j = threadIdx.x; j < m; j += TPB) ssrc[s0 + j] = stage[j];
    if (b == 0 && threadIdx.x == 0) offs[n] = e;
}

// ---------------- feature kernels ----------------

// G = x * dinv[row], fp32 -> fp16, half8-wide (D=16 -> 2 chunks)
__global__ void k_scale(const float* __restrict__ x, const float* __restrict__ dinv,
                        half_t* __restrict__ G, int n) {
    int idx = blockIdx.x * blockDim.x + threadIdx.x;
    if (idx >= n * 2) return;
    float d = dinv[idx >> 1];
    float8v v = ((const float8v*)x)[idx];
    half8 h;
#pragma unroll
    for (int q = 0; q < 8; ++q) h[q] = (half_t)(v[q] * d);
    ((half8*)G)[idx] = h;
}

// Fused gather + GEMM conv layer.
// Round-7 lesson: gather is LATENCY-bound (VALUBusy 23%, HBM 13%, occ 21%).
// Fix: 4-way unrolled edge loop (4 loads in flight), launch_bounds(,4)
// (4 blocks/CU), and fp16 W tile for conv3 (LDS 41.5->25 KB).
template<int DI, int DO, int R, bool SCALE, bool OUT_HALF, bool WHALF>
__global__ void __launch_bounds__(TPB, 4)
k_conv(const int* __restrict__ offs, const int* __restrict__ ssrc,
       const half_t* __restrict__ G, const float* __restrict__ dinv,
       const float* __restrict__ W, const float* __restrict__ b,
       void* __restrict__ outp, int n) {
    constexpr int CT = DO / 4;
    constexpr int RT = TPB / CT;
    constexpr int TM = RT * R;
    constexpr int K4 = DI / 4;
    constexpr int PX = K4 + 1;
    constexpr int C  = DI / 8;
    static_assert(TM * C == TPB, "gather/gemm tile mismatch");
    __shared__ float4 sW4[WHALF ? 1 : DI * CT];
    __shared__ half4  sWh[WHALF ? DI * CT : 1];
    __shared__ float4 sX4[TM * PX];
    const int tid = threadIdx.x;
    const int r0 = blockIdx.x * TM;

    const float4* Wg = (const float4*)W;
    for (int t = tid; t < DI * CT; t += TPB) {
        float4 w = Wg[t];
        if (WHALF) {
            half4 h;
            h.x = (half_t)w.x; h.y = (half_t)w.y;
            h.z = (half_t)w.z; h.w = (half_t)w.w;
            sWh[t] = h;
        } else {
            sW4[t] = w;
        }
    }

    // ---- gather phase: each thread aggregates one half8 chunk of one row ----
    {
        int gr = tid / C;
        int gc = tid - gr * C;
        int row = r0 + gr;
        float8v acc;
#pragma unroll
        for (int q = 0; q < 8; ++q) acc[q] = 0.f;
        if (row < n) {
            const half8* Grow = (const half8*)G;
            half8 hs = Grow[(size_t)row * C + gc];
#pragma unroll
            for (int q = 0; q < 8; ++q) acc[q] = (float)hs[q];
            int s0 = offs[row], s1 = offs[row + 1];
            int j = s0;
            for (; j + 3 < s1; j += 4) {             // 4 independent loads in flight
                int sa = ssrc[j], sb = ssrc[j + 1];
                int sc = ssrc[j + 2], sd = ssrc[j + 3];
                half8 ga = Grow[(size_t)sa * C + gc];
                half8 gb = Grow[(size_t)sb * C + gc];
                half8 gch = Grow[(size_t)sc * C + gc];
                half8 gd = Grow[(size_t)sd * C + gc];
#pragma unroll
                for (int q = 0; q < 8; ++q)
                    acc[q] += ((float)ga[q] + (float)gb[q]) + ((float)gch[q] + (float)gd[q]);
            }
            for (; j < s1; ++j) {
                half8 ga = Grow[(size_t)ssrc[j] * C + gc];
#pragma unroll
                for (int q = 0; q < 8; ++q) acc[q] += (float)ga[q];
            }
            float di = dinv[row];
#pragma unroll
            for (int q = 0; q < 8; ++q) acc[q] *= di;
        }
        sX4[gr * PX + 2 * gc]     = make_float4(acc[0], acc[1], acc[2], acc[3]);
        sX4[gr * PX + 2 * gc + 1] = make_float4(acc[4], acc[5], acc[6], acc[7]);
    }
    __syncthreads();

    // ---- GEMM phase ----
    const int c = tid & (CT - 1);
    const int rg = tid / CT;
    const int rbase = rg * R;
    float4 acc[R];
#pragma unroll
    for (int r = 0; r < R; ++r) acc[r] = make_float4(0.f, 0.f, 0.f, 0.f);

#pragma unroll 2
    for (int k4 = 0; k4 < K4; ++k4) {
        float4 xv[R];
#pragma unroll
        for (int r = 0; r < R; ++r) xv[r] = sX4[(rbase + r) * PX + k4];
#pragma unroll
        for (int kk = 0; kk < 4; ++kk) {
            float4 wv;
            if (WHALF) {
                half4 wh = sWh[(k4 * 4 + kk) * CT + c];
                wv = make_float4((float)wh.x, (float)wh.y, (float)wh.z, (float)wh.w);
            } else {
                wv = sW4[(k4 * 4 + kk) * CT + c];
            }
#pragma unroll
            for (int r = 0; r < R; ++r) {
                float xs = (kk == 0) ? xv[r].x : (kk == 1) ? xv[r].y
                         : (kk == 2) ? xv[r].z : xv[r].w;
                acc[r].x += xs * wv.x; acc[r].y += xs * wv.y;
                acc[r].z += xs * wv.z; acc[r].w += xs * wv.w;
            }
        }
    }

    float4 bc = ((const float4*)b)[c];
#pragma unroll
    for (int r = 0; r < R; ++r) {
        int row = r0 + rbase + r;
        if (row < n) {
            float4 o;
            o.x = fmaxf(acc[r].x + bc.x, 0.f);
            o.y = fmaxf(acc[r].y + bc.y, 0.f);
            o.z = fmaxf(acc[r].z + bc.z, 0.f);
            o.w = fmaxf(acc[r].w + bc.w, 0.f);
            if (SCALE) {
                float d = dinv[row];
                o.x *= d; o.y *= d; o.z *= d; o.w *= d;
            }
            if (OUT_HALF) {
                half4 h;
                h.x = (half_t)o.x; h.y = (half_t)o.y;
                h.z = (half_t)o.z; h.w = (half_t)o.w;
                ((half4*)outp)[(size_t)row * CT + c] = h;
            } else {
                ((float4*)outp)[(size_t)row * CT + c] = o;
            }
        }
    }
}

// Fused dense head: out = relu(relu(relu(X@W1+b1)@W2+b2)@W3+b3)
__global__ void __launch_bounds__(256, 2)
k_head(const half_t* __restrict__ X,
       const float* __restrict__ W1, const float* __restrict__ b1,
       const float* __restrict__ W2, const float* __restrict__ b2,
       const float* __restrict__ W3, const float* __restrict__ b3,
       float* __restrict__ out, int n) {
    __shared__ half_t hW1[128 * 64];
    __shared__ half_t hW2[64 * 32];
    __shared__ half_t hW3[32 * 16];
    __shared__ float h1[64 * 65];
    __shared__ float h2[64 * 33];
    const int tid = threadIdx.x;
    const int r0 = blockIdx.x * 64;

    for (int t = tid; t < 128 * 64; t += 256) hW1[t] = (half_t)W1[t];
    for (int t = tid; t < 64 * 32; t += 256) hW2[t] = (half_t)W2[t];
    for (int t = tid; t < 32 * 16; t += 256) hW3[t] = (half_t)W3[t];
    __syncthreads();

    // ---- stage 1: 128 -> 64 ----
    {
        const int c4 = tid & 15;
        const int rowg = tid >> 4;
        const half8* Xr = (const half8*)X;
        float acc[4][4];
#pragma unroll
        for (int r = 0; r < 4; ++r)
#pragma unroll
            for (int j = 0; j < 4; ++j) acc[r][j] = 0.f;
        for (int k8 = 0; k8 < 16; ++k8) {
            half8 xh[4];
#pragma unroll
            for (int r = 0; r < 4; ++r) {
                int row = r0 + rowg * 4 + r;
                if (row < n) xh[r] = Xr[(size_t)row * 16 + k8];
                else { half8 z; for (int q = 0; q < 8; ++q) z[q] = (half_t)0.f; xh[r] = z; }
            }
#pragma unroll
            for (int q = 0; q < 8; ++q) {
                int k = k8 * 8 + q;
                half4 w = *(const half4*)&hW1[k * 64 + c4 * 4];
                float w0 = (float)w.x, w1 = (float)w.y, w2 = (float)w.z, w3 = (float)w.w;
#pragma unroll
                for (int r = 0; r < 4; ++r) {
                    float xs = (float)xh[r][q];
                    acc[r][0] += xs * w0; acc[r][1] += xs * w1;
                    acc[r][2] += xs * w2; acc[r][3] += xs * w3;
                }
            }
        }
        float4 bc = ((const float4*)b1)[c4];
#pragma unroll
        for (int r = 0; r < 4; ++r) {
            int rl = rowg * 4 + r;
            h1[rl * 65 + c4 * 4 + 0] = fmaxf(acc[r][0] + bc.x, 0.f);
            h1[rl * 65 + c4 * 4 + 1] = fmaxf(acc[r][1] + bc.y, 0.f);
            h1[rl * 65 + c4 * 4 + 2] = fmaxf(acc[r][2] + bc.z, 0.f);
            h1[rl * 65 + c4 * 4 + 3] = fmaxf(acc[r][3] + bc.w, 0.f);
        }
    }
    __syncthreads();

    // ---- stage 2: 64 -> 32 ----
    {
        const int c4 = tid & 7;
        const int rowg = tid >> 3;
        float acc[2][4];
#pragma unroll
        for (int r = 0; r < 2; ++r)
#pragma unroll
            for (int j = 0; j < 4; ++j) acc[r][j] = 0.f;
#pragma unroll 4
        for (int k = 0; k < 64; ++k) {
            half4 w = *(const half4*)&hW2[k * 32 + c4 * 4];
            float w0 = (float)w.x, w1 = (float)w.y, w2 = (float)w.z, w3 = (float)w.w;
#pragma unroll
            for (int r = 0; r < 2; ++r) {
                float xs = h1[(rowg * 2 + r) * 65 + k];
                acc[r][0] += xs * w0; acc[r][1] += xs * w1;
                acc[r][2] += xs * w2; acc[r][3] += xs * w3;
            }
        }
        float4 bc = ((const float4*)b2)[c4];
#pragma unroll
        for (int r = 0; r < 2; ++r) {
            int rl = rowg * 2 + r;
            h2[rl * 33 + c4 * 4 + 0] = fmaxf(acc[r][0] + bc.x, 0.f);
            h2[rl * 33 + c4 * 4 + 1] = fmaxf(acc[r][1] + bc.y, 0.f);
            h2[rl * 33 + c4 * 4 + 2] = fmaxf(acc[r][2] + bc.z, 0.f);
            h2[rl * 33 + c4 * 4 + 3] = fmaxf(acc[r][3] + bc.w, 0.f);
        }
    }
    __syncthreads();

    // ---- stage 3: 32 -> 16 ----
    {
        const int c4 = tid & 3;
        const int rl = tid >> 2;
        float a0 = 0.f, a1 = 0.f, a2 = 0.f, a3 = 0.f;
#pragma unroll 4
        for (int k = 0; k < 32; ++k) {
            half4 w = *(const half4*)&hW3[k * 16 + c4 * 4];
            float xs = h2[rl * 33 + k];
            a0 += xs * (float)w.x; a1 += xs * (float)w.y;
            a2 += xs * (float)w.z; a3 += xs * (float)w.w;
        }
        int row = r0 + rl;
        if (row < n) {
            float4 bc = ((const float4*)b3)[c4];
            float4 o;
            o.x = fmaxf(a0 + bc.x, 0.f);
            o.y = fmaxf(a1 + bc.y, 0.f);
            o.z = fmaxf(a2 + bc.z, 0.f);
            o.w = fmaxf(a3 + bc.w, 0.f);
            ((float4*)out)[(size_t)row * 4 + c4] = o;
        }
    }
}

extern "C" void kernel_launch(void* const* d_in, const int* in_sizes, int n_in,
                              void* d_out, int out_size, void* d_ws, size_t ws_size,
                              hipStream_t stream) {
    const float* x   = (const float*)d_in[0];
    const int*   ei  = (const int*)d_in[1];
    const float* W1  = (const float*)d_in[2];
    const float* bb1 = (const float*)d_in[3];
    const float* W2  = (const float*)d_in[4];
    const float* bb2 = (const float*)d_in[5];
    const float* W3  = (const float*)d_in[6];
    const float* bb3 = (const float*)d_in[7];
    const float* Wl1 = (const float*)d_in[8];
    const float* bl1 = (const float*)d_in[9];
    const float* Wl2 = (const float*)d_in[10];
    const float* bl2 = (const float*)d_in[11];
    const float* Wl3 = (const float*)d_in[12];
    const float* bl3 = (const float*)d_in[13];
    float* out = (float*)d_out;

    const int n = in_sizes[0] / 16;   // 50000
    const int e = in_sizes[1] / 2;    // 800000
    const int* src = ei;
    const int* dst = ei + e;
    const int nb = cdiv(n, 256);      // 196 coarse buckets

    char* p = (char*)d_ws;
    auto alloc = [&](size_t bytes) {
        char* r = p;
        p += (bytes + 255) & ~(size_t)255;
        return r;
    };
    float*        dinv   = (float*)        alloc((size_t)n * 4);
    int*          offs   = (int*)          alloc((size_t)(n + 1) * 4);
    int*          gcnt   = (int*)          alloc(256 * 4);
    int*          bstart = (int*)          alloc(257 * 4);
    int*          bcur   = (int*)          alloc(256 * 4);
    unsigned int* gbuf   = (unsigned int*) alloc((size_t)e * 4);
    int*          ssrc   = (int*)          alloc((size_t)e * 4);
    half_t*       H1     = (half_t*)       alloc((size_t)n * 64 * 2);
    half_t*       H2     = (half_t*)       alloc((size_t)n * 32 * 2);
    half_t*       X3h    = (half_t*)       alloc((size_t)n * 128 * 2);

    // ---- CSR + dinv (all-coalesced bucket sort) ----
    k_zero_int<<<1, 256, 0, stream>>>(gcnt, nb);
    k_bhist<<<512, TPB, 0, stream>>>(dst, gcnt, e, nb);
    k_bscan<<<1, 256, 0, stream>>>(gcnt, bstart, bcur, nb, e);
    k_binscatter<<<cdiv(e, TE), TPB, 0, stream>>>(src, dst, bcur, gbuf, e, nb);
    k_csr<<<nb, TPB, 0, stream>>>(gbuf, bstart, offs, dinv, ssrc, n, e);

    // ---- convs (fused gather+GEMM) ----
    k_scale<<<cdiv(n * 2, TPB), TPB, 0, stream>>>(x, dinv, H1, n);
    k_conv<16, 32, 4, true, true, false><<<cdiv(n, 128), TPB, 0, stream>>>(
        offs, ssrc, H1, dinv, W1, bb1, H2, n);
    k_conv<32, 64, 4, true, true, false><<<cdiv(n, 64), TPB, 0, stream>>>(
        offs, ssrc, H2, dinv, W2, bb2, H1, n);
    k_conv<64, 128, 4, false, true, true><<<cdiv(n, 32), TPB, 0, stream>>>(
        offs, ssrc, H1, dinv, W3, bb3, X3h, n);

    // ---- fused dense head ----
    k_head<<<cdiv(n, 64), 256, 0, stream>>>(X3h, Wl1, bl1, Wl2, bl2, Wl3, bl3, out, n);
}